// Round 1
// baseline (1387.798 us; speedup 1.0000x reference)
//
#include <hip/hip_runtime.h>
#include <stdint.h>

// Problem constants (B=4, S=2048 -> T=8192 tokens)
#define T_TOK 8192
#define DIM   1024
#define NEXP  8
#define HID   2816

typedef __bf16 bf16x8 __attribute__((ext_vector_type(8)));
typedef float  f32x4  __attribute__((ext_vector_type(4)));

typedef __attribute__((address_space(3))) uint32_t lds_u32_t;
typedef __attribute__((address_space(1))) const uint32_t gbl_u32_t;

// async global->LDS, 16B per lane. LDS dest = wave-uniform base + lane*16.
__device__ __forceinline__ void gl_lds16(const void* g, void* l) {
    __builtin_amdgcn_global_load_lds((gbl_u32_t*)g, (lds_u32_t*)l, 16, 0, 0);
}

__device__ __forceinline__ uint32_t f2bf_u(float f) {
    uint32_t u = __builtin_bit_cast(uint32_t, f);
    return u + 0x7fffu + ((u >> 16) & 1u);   // RNE to bf16, top 16 bits valid
}
__device__ __forceinline__ uint32_t pack2(float a, float b) {
    return (f2bf_u(a) >> 16) | (f2bf_u(b) & 0xffff0000u);
}

// ---------------------------------------------------------------------------
// Kernel 0: fp32 -> bf16 conversion (weights + x), 8 floats/thread.
// ---------------------------------------------------------------------------
__global__ __launch_bounds__(256) void cvt_k(
    const float* __restrict__ s, unsigned short* __restrict__ d, int n8)
{
    int i = blockIdx.x * 256 + threadIdx.x;
    if (i < n8) {
        const float4* sp = (const float4*)(s + (size_t)i * 8);
        float4 a = sp[0], b = sp[1];
        uint4 o;
        o.x = pack2(a.x, a.y); o.y = pack2(a.z, a.w);
        o.z = pack2(b.x, b.y); o.w = pack2(b.z, b.w);
        ((uint4*)d)[i] = o;
    }
}

// ---------------------------------------------------------------------------
// Kernel 1: router. One wave per token, fp64 logits, top-2 + softmax,
// per-expert gather lists via atomic counters.
// ---------------------------------------------------------------------------
__global__ __launch_bounds__(256) void router_k(
    const float* __restrict__ x, const float* __restrict__ gw,
    int* __restrict__ cnt, int* __restrict__ slot_list,
    float* __restrict__ slot_w)
{
    const int wave = threadIdx.x >> 6, lane = threadIdx.x & 63;
    const int t = blockIdx.x * 4 + wave;
    const float4* xp = (const float4*)(x + (size_t)t * DIM + lane * 16);
    float4 xv[4];
#pragma unroll
    for (int i = 0; i < 4; ++i) xv[i] = xp[i];

    double lg[NEXP];
#pragma unroll
    for (int e = 0; e < NEXP; ++e) {
        const float4* gp = (const float4*)(gw + (size_t)e * DIM + lane * 16);
        double s = 0.0;
#pragma unroll
        for (int i = 0; i < 4; ++i) {
            float4 g = gp[i];
            s += (double)xv[i].x * g.x + (double)xv[i].y * g.y +
                 (double)xv[i].z * g.z + (double)xv[i].w * g.w;
        }
#pragma unroll
        for (int m = 32; m >= 1; m >>= 1) s += __shfl_xor(s, m, 64);
        lg[e] = s;
    }

    if (lane == 0) {
        int e0 = 0; double b0 = lg[0];
#pragma unroll
        for (int e = 1; e < NEXP; ++e)
            if (lg[e] > b0) { b0 = lg[e]; e0 = e; }
        int e1 = -1; double b1 = -1.0e300;
#pragma unroll
        for (int e = 0; e < NEXP; ++e)
            if (e != e0 && lg[e] > b1) { b1 = lg[e]; e1 = e; }

        float p0 = (float)(1.0 / (1.0 + exp(b1 - b0)));
        float p1 = 1.0f - p0;

        int pos0 = atomicAdd(&cnt[e0], 1);
        slot_list[e0 * T_TOK + pos0] = 2 * t;
        slot_w[2 * t] = p0;
        int pos1 = atomicAdd(&cnt[e1], 1);
        slot_list[e1 * T_TOK + pos1] = 2 * t + 1;
        slot_w[2 * t + 1] = p1;
    }
}

// ---------------------------------------------------------------------------
// Kernel 2: gathered GEMM, fused w1/w3 + SwiGLU. All-bf16 inputs, staged via
// global_load_lds dwordx4. C-tile 128 slots x (64+64) hid.
// LDS layout [quarter][row][8 bf16]: each 16-lane ds_read_b128 group reads
// 256B contiguous -> zero bank conflicts (the old [row][32] layout had a
// 64B row stride = 8-way conflict, SQ_LDS_BANK_CONFLICT 2.4e7).
// Staging permutation is applied on the per-lane GLOBAL source address
// (global_load_lds LDS dest is linear, lane*16): instruction q stages
// chunk q (elements k0+q*8..+8) of 64 rows, lane l -> row l.
// grid (HID/64=44, ceilT/128, NEXP), early-exit on empty m-block.
// ---------------------------------------------------------------------------
__global__ __launch_bounds__(256) void ffn1_k(
    const unsigned short* __restrict__ xb, const unsigned short* __restrict__ w1b,
    const unsigned short* __restrict__ w3b, const int* __restrict__ cnt,
    const int* __restrict__ slot_list, unsigned short* __restrict__ h_ws)
{
    __shared__ unsigned short As[4][128][8];
    __shared__ unsigned short B1s[4][64][8];
    __shared__ unsigned short B2s[4][64][8];
    __shared__ int slots_s[128];

    const int e = blockIdx.z;
    const int cntE = cnt[e];
    const int m0 = blockIdx.y * 128;
    if (m0 >= cntE) return;
    const int n0 = blockIdx.x * 64;
    const int tid = threadIdx.x;
    const int wave = tid >> 6, lane = tid & 63;

    if (tid < 128) {
        int idx = m0 + tid;
        slots_s[tid] = (idx < cntE) ? slot_list[e * T_TOK + idx] : -1;
    }
    __syncthreads();

    // staging: 4 global_load_lds per wave per k-step (one per 16B quarter).
    // waves 0,1 -> A rows (gathered tokens); wave 2 -> w1 rows; wave 3 -> w3.
    const unsigned short* gbase;   // per-lane row base
    unsigned short* lbase;         // wave-uniform LDS base (quarter 0)
    int lstride;                   // ushorts per quarter plane
    if (wave < 2) {
        int slot = slots_s[wave * 64 + lane];
        int tok = (slot >= 0) ? (slot >> 1) : 0;   // clamp tail to token 0
        gbase = xb + (size_t)tok * DIM;
        lbase = &As[0][wave * 64][0];
        lstride = 128 * 8;
    } else if (wave == 2) {
        gbase = w1b + ((size_t)e * HID + n0 + lane) * DIM;
        lbase = &B1s[0][0][0];
        lstride = 64 * 8;
    } else {
        gbase = w3b + ((size_t)e * HID + n0 + lane) * DIM;
        lbase = &B2s[0][0][0];
        lstride = 64 * 8;
    }

    const int wm = wave >> 1, wn = wave & 1;
    const int lrow = lane & 15, quad = lane >> 4;

    f32x4 acc1[4][2], acc2[4][2];
    const f32x4 zf = {0.f, 0.f, 0.f, 0.f};
#pragma unroll
    for (int mi = 0; mi < 4; ++mi)
#pragma unroll
        for (int ni = 0; ni < 2; ++ni) { acc1[mi][ni] = zf; acc2[mi][ni] = zf; }

    for (int k0 = 0; k0 < DIM; k0 += 32) {
#pragma unroll
        for (int q = 0; q < 4; ++q)
            gl_lds16(gbase + q * 8, lbase + q * lstride);
        gbase += 32;
        __syncthreads();

        bf16x8 af[4], b1f[2], b2f[2];
#pragma unroll
        for (int mi = 0; mi < 4; ++mi)
            af[mi] = *(const bf16x8*)&As[quad][wm * 64 + mi * 16 + lrow][0];
#pragma unroll
        for (int ni = 0; ni < 2; ++ni) {
            b1f[ni] = *(const bf16x8*)&B1s[quad][wn * 32 + ni * 16 + lrow][0];
            b2f[ni] = *(const bf16x8*)&B2s[quad][wn * 32 + ni * 16 + lrow][0];
        }
#pragma unroll
        for (int mi = 0; mi < 4; ++mi)
#pragma unroll
            for (int ni = 0; ni < 2; ++ni) {
                acc1[mi][ni] = __builtin_amdgcn_mfma_f32_16x16x32_bf16(
                    af[mi], b1f[ni], acc1[mi][ni], 0, 0, 0);
                acc2[mi][ni] = __builtin_amdgcn_mfma_f32_16x16x32_bf16(
                    af[mi], b2f[ni], acc2[mi][ni], 0, 0, 0);
            }
        __syncthreads();
    }

    // epilogue: h = silu(a1) * a3 -> bf16 h_ws[slot, n]
#pragma unroll
    for (int mi = 0; mi < 4; ++mi) {
#pragma unroll
        for (int r = 0; r < 4; ++r) {
            int mloc = wm * 64 + mi * 16 + quad * 4 + r;
            int slot = slots_s[mloc];
            if (slot >= 0) {
                unsigned short* hrow =
                    h_ws + (size_t)slot * HID + n0 + wn * 32 + lrow;
#pragma unroll
                for (int ni = 0; ni < 2; ++ni) {
                    float a1 = acc1[mi][ni][r], a3 = acc2[mi][ni][r];
                    float hv = (a1 / (1.f + __expf(-a1))) * a3;
                    hrow[ni * 16] = (unsigned short)(f2bf_u(hv) >> 16);
                }
            }
        }
    }
}

// ---------------------------------------------------------------------------
// Kernel 3: gathered GEMM y = h @ w2^T, scale by routing weight, atomicAdd
// into out. C-tile 128 x 128. Same conflict-free [quarter][row][8] LDS layout.
// grid (DIM/128=8, ceilT/128, NEXP).
// ---------------------------------------------------------------------------
__global__ __launch_bounds__(256) void ffn2_k(
    const unsigned short* __restrict__ h_ws, const unsigned short* __restrict__ w2b,
    const int* __restrict__ cnt, const int* __restrict__ slot_list,
    const float* __restrict__ slot_w, float* __restrict__ out)
{
    __shared__ unsigned short As[4][128][8];
    __shared__ unsigned short Bs[4][128][8];
    __shared__ int slots_s[128];
    __shared__ float wgt_s[128];

    const int e = blockIdx.z;
    const int cntE = cnt[e];
    const int m0 = blockIdx.y * 128;
    if (m0 >= cntE) return;
    const int n0 = blockIdx.x * 128;
    const int tid = threadIdx.x;
    const int wave = tid >> 6, lane = tid & 63;

    if (tid < 128) {
        int idx = m0 + tid;
        int s = (idx < cntE) ? slot_list[e * T_TOK + idx] : -1;
        slots_s[tid] = s;
        wgt_s[tid] = (s >= 0) ? slot_w[s] : 0.f;
    }
    __syncthreads();

    // staging: waves 0,1 -> A (gathered h rows); waves 2,3 -> w2 rows.
    const unsigned short* gbase;
    unsigned short* lbase;
    const int lstride = 128 * 8;
    if (wave < 2) {
        int slot = slots_s[wave * 64 + lane];
        int s = (slot >= 0) ? slot : 0;
        gbase = h_ws + (size_t)s * HID;
        lbase = &As[0][wave * 64][0];
    } else {
        int row = (wave - 2) * 64 + lane;
        gbase = w2b + ((size_t)e * DIM + n0 + row) * HID;
        lbase = &Bs[0][(wave - 2) * 64][0];
    }

    const int wm = wave >> 1, wn = wave & 1;
    const int lrow = lane & 15, quad = lane >> 4;

    f32x4 acc[4][4];
    const f32x4 zf = {0.f, 0.f, 0.f, 0.f};
#pragma unroll
    for (int mi = 0; mi < 4; ++mi)
#pragma unroll
        for (int ni = 0; ni < 4; ++ni) acc[mi][ni] = zf;

    for (int k0 = 0; k0 < HID; k0 += 32) {
#pragma unroll
        for (int q = 0; q < 4; ++q)
            gl_lds16(gbase + q * 8, lbase + q * lstride);
        gbase += 32;
        __syncthreads();

        bf16x8 af[4], bf[4];
#pragma unroll
        for (int mi = 0; mi < 4; ++mi)
            af[mi] = *(const bf16x8*)&As[quad][wm * 64 + mi * 16 + lrow][0];
#pragma unroll
        for (int ni = 0; ni < 4; ++ni)
            bf[ni] = *(const bf16x8*)&Bs[quad][wn * 64 + ni * 16 + lrow][0];
#pragma unroll
        for (int mi = 0; mi < 4; ++mi)
#pragma unroll
            for (int ni = 0; ni < 4; ++ni)
                acc[mi][ni] = __builtin_amdgcn_mfma_f32_16x16x32_bf16(
                    af[mi], bf[ni], acc[mi][ni], 0, 0, 0);
        __syncthreads();
    }

#pragma unroll
    for (int mi = 0; mi < 4; ++mi) {
#pragma unroll
        for (int r = 0; r < 4; ++r) {
            int mloc = wm * 64 + mi * 16 + quad * 4 + r;
            int slot = slots_s[mloc];
            if (slot >= 0) {
                int tok = slot >> 1;
                float w = wgt_s[mloc];
                float* orow = out + (size_t)tok * DIM + n0 + wn * 64 + lrow;
#pragma unroll
                for (int ni = 0; ni < 4; ++ni)
                    atomicAdd(&orow[ni * 16], acc[mi][ni][r] * w);
            }
        }
    }
}

// ---------------------------------------------------------------------------
// Workspace layout (bytes, all 256-aligned):
//   [0, 256)                 cnt[8]                (memset 0 per launch)
//   [256, +262144)           slot_list[8][8192]
//   [+262144, +65536)        slot_w[16384]
//   [327936, +92274688)      h_ws   bf16 [16384][2816]
//   [92602624, +16777216)    x_bf   bf16 [8192][1024]
//   [109379840, +46137344)   w1_bf  bf16 [8][2816][1024]
//   [155517184, +46137344)   w3_bf
//   [201654528, +46137344)   w2_bf  bf16 [8][1024][2816]
//   total ~247.8 MB
// ---------------------------------------------------------------------------
extern "C" void kernel_launch(void* const* d_in, const int* in_sizes, int n_in,
                              void* d_out, int out_size, void* d_ws, size_t ws_size,
                              hipStream_t stream) {
    const float* x  = (const float*)d_in[0];
    const float* gw = (const float*)d_in[1];
    const float* w1 = (const float*)d_in[2];
    const float* w2 = (const float*)d_in[3];
    const float* w3 = (const float*)d_in[4];
    float* out = (float*)d_out;

    char* ws = (char*)d_ws;
    int*   cnt       = (int*)ws;
    int*   slot_list = (int*)(ws + 256);
    float* slot_w    = (float*)(ws + 256 + NEXP * T_TOK * 4);
    unsigned short* h_ws = (unsigned short*)(ws + 327936);
    unsigned short* x_bf = (unsigned short*)(ws + 92602624);
    unsigned short* w1_bf = (unsigned short*)(ws + 109379840);
    unsigned short* w3_bf = (unsigned short*)(ws + 155517184);
    unsigned short* w2_bf = (unsigned short*)(ws + 201654528);

    hipMemsetAsync(cnt, 0, 256, stream);
    hipMemsetAsync(out, 0, (size_t)T_TOK * DIM * sizeof(float), stream);

    const int nx = T_TOK * DIM / 8;              // 1048576
    const int nw = NEXP * HID * DIM / 8;         // 2883584
    cvt_k<<<(nx + 255) / 256, 256, 0, stream>>>(x, x_bf, nx);
    cvt_k<<<(nw + 255) / 256, 256, 0, stream>>>(w1, w1_bf, nw);
    cvt_k<<<(nw + 255) / 256, 256, 0, stream>>>(w3, w3_bf, nw);
    cvt_k<<<(nw + 255) / 256, 256, 0, stream>>>(w2, w2_bf, nw);

    router_k<<<T_TOK / 4, 256, 0, stream>>>(x, gw, cnt, slot_list, slot_w);
    ffn1_k<<<dim3(HID / 64, T_TOK / 128, NEXP), 256, 0, stream>>>(
        x_bf, w1_bf, w3_bf, cnt, slot_list, h_ws);
    ffn2_k<<<dim3(DIM / 128, T_TOK / 128, NEXP), 256, 0, stream>>>(
        h_ws, w2_bf, cnt, slot_list, slot_w, out);
}

// Round 2
// 929.376 us; speedup vs baseline: 1.4933x; 1.4933x over previous
//
#include <hip/hip_runtime.h>
#include <stdint.h>

// Problem constants (B=4, S=2048 -> T=8192 tokens)
#define T_TOK 8192
#define DIM   1024
#define NEXP  8
#define HID   2816

typedef __bf16 bf16x8 __attribute__((ext_vector_type(8)));
typedef float  f32x4  __attribute__((ext_vector_type(4)));

typedef __attribute__((address_space(3))) uint32_t lds_u32_t;
typedef __attribute__((address_space(1))) const uint32_t gbl_u32_t;

// async global->LDS, 16B per lane. LDS dest = wave-uniform base + lane*16.
__device__ __forceinline__ void gl_lds16(const void* g, void* l) {
    __builtin_amdgcn_global_load_lds((gbl_u32_t*)g, (lds_u32_t*)l, 16, 0, 0);
}

__device__ __forceinline__ uint32_t f2bf_u(float f) {
    uint32_t u = __builtin_bit_cast(uint32_t, f);
    return u + 0x7fffu + ((u >> 16) & 1u);   // RNE to bf16, top 16 bits valid
}
__device__ __forceinline__ uint32_t pack2(float a, float b) {
    return (f2bf_u(a) >> 16) | (f2bf_u(b) & 0xffff0000u);
}

// ---------------------------------------------------------------------------
// LDS quarter swizzle: tile rows are [row][32 bf16] = [row][4 quarters x 16B].
// Physical quarter p holds global quarter q = p ^ ((row>>1)&3).
//  - write side (global_load_lds, linear LDS dest): lane l = rr*4+p sources
//    global chunk (p ^ ((rr>>1)&3)) of row rr -> same 64B segment per 4-lane
//    group as the unswizzled version => coalescing preserved (round-1 lesson:
//    per-lane-row scatter killed perf; this permutes only WITHIN the 64B row
//    chunk).
//  - read side (ds_read_b128): lane l reads row (l&15) at physical quarter
//    (l>>4) ^ (((l&15)>>1)&3). Banks for lanes 0..15: quads
//    {0,16,4,20,8,24,12,28}+... every bank hit exactly 2x per 16 lanes =
//    2-way = free (vs 8-way for the linear layout, SQ_LDS_BANK_CONFLICT
//    2.4e7 in round 0).
//  All row-block bases are multiples of 8 so (row>>1)&3 == (lrow>>1)&3 on
//  both sides.
// ---------------------------------------------------------------------------

// ---------------------------------------------------------------------------
// Kernel 0: fp32 -> bf16 conversion (weights + x), 8 floats/thread.
// ---------------------------------------------------------------------------
__global__ __launch_bounds__(256) void cvt_k(
    const float* __restrict__ s, unsigned short* __restrict__ d, int n8)
{
    int i = blockIdx.x * 256 + threadIdx.x;
    if (i < n8) {
        const float4* sp = (const float4*)(s + (size_t)i * 8);
        float4 a = sp[0], b = sp[1];
        uint4 o;
        o.x = pack2(a.x, a.y); o.y = pack2(a.z, a.w);
        o.z = pack2(b.x, b.y); o.w = pack2(b.z, b.w);
        ((uint4*)d)[i] = o;
    }
}

// ---------------------------------------------------------------------------
// Kernel 1: router. One wave per token, fp64 logits, top-2 + softmax,
// per-expert gather lists via atomic counters.
// ---------------------------------------------------------------------------
__global__ __launch_bounds__(256) void router_k(
    const float* __restrict__ x, const float* __restrict__ gw,
    int* __restrict__ cnt, int* __restrict__ slot_list,
    float* __restrict__ slot_w)
{
    const int wave = threadIdx.x >> 6, lane = threadIdx.x & 63;
    const int t = blockIdx.x * 4 + wave;
    const float4* xp = (const float4*)(x + (size_t)t * DIM + lane * 16);
    float4 xv[4];
#pragma unroll
    for (int i = 0; i < 4; ++i) xv[i] = xp[i];

    double lg[NEXP];
#pragma unroll
    for (int e = 0; e < NEXP; ++e) {
        const float4* gp = (const float4*)(gw + (size_t)e * DIM + lane * 16);
        double s = 0.0;
#pragma unroll
        for (int i = 0; i < 4; ++i) {
            float4 g = gp[i];
            s += (double)xv[i].x * g.x + (double)xv[i].y * g.y +
                 (double)xv[i].z * g.z + (double)xv[i].w * g.w;
        }
#pragma unroll
        for (int m = 32; m >= 1; m >>= 1) s += __shfl_xor(s, m, 64);
        lg[e] = s;
    }

    if (lane == 0) {
        int e0 = 0; double b0 = lg[0];
#pragma unroll
        for (int e = 1; e < NEXP; ++e)
            if (lg[e] > b0) { b0 = lg[e]; e0 = e; }
        int e1 = -1; double b1 = -1.0e300;
#pragma unroll
        for (int e = 0; e < NEXP; ++e)
            if (e != e0 && lg[e] > b1) { b1 = lg[e]; e1 = e; }

        float p0 = (float)(1.0 / (1.0 + exp(b1 - b0)));
        float p1 = 1.0f - p0;

        int pos0 = atomicAdd(&cnt[e0], 1);
        slot_list[e0 * T_TOK + pos0] = 2 * t;
        slot_w[2 * t] = p0;
        int pos1 = atomicAdd(&cnt[e1], 1);
        slot_list[e1 * T_TOK + pos1] = 2 * t + 1;
        slot_w[2 * t + 1] = p1;
    }
}

// ---------------------------------------------------------------------------
// Kernel 2: gathered GEMM, fused w1/w3 + SwiGLU. All-bf16 inputs, staged via
// global_load_lds dwordx4 with the quarter swizzle described above.
// C-tile 128 slots x (64+64) hid. grid (HID/64=44, ceilT/128, NEXP).
// ---------------------------------------------------------------------------
__global__ __launch_bounds__(256) void ffn1_k(
    const unsigned short* __restrict__ xb, const unsigned short* __restrict__ w1b,
    const unsigned short* __restrict__ w3b, const int* __restrict__ cnt,
    const int* __restrict__ slot_list, unsigned short* __restrict__ h_ws)
{
    __shared__ unsigned short As[128 * 32];
    __shared__ unsigned short B1s[64 * 32];
    __shared__ unsigned short B2s[64 * 32];
    __shared__ int slots_s[128];

    const int e = blockIdx.z;
    const int cntE = cnt[e];
    const int m0 = blockIdx.y * 128;
    if (m0 >= cntE) return;
    const int n0 = blockIdx.x * 64;
    const int tid = threadIdx.x;
    const int wave = tid >> 6, lane = tid & 63;

    if (tid < 128) {
        int idx = m0 + tid;
        slots_s[tid] = (idx < cntE) ? slot_list[e * T_TOK + idx] : -1;
    }
    __syncthreads();

    // staging: 4 global_load_lds per wave per k-step, each instr = 16 rows x
    // 64B (coalesced). Lane l: row rr=l>>2, physical quarter p=l&3, global
    // chunk qsw = p ^ ((rr>>1)&3)  (swizzle within the 64B row chunk).
    // waves 0,1 -> A rows (gathered tokens); wave 2 -> w1 rows; wave 3 -> w3.
    const int rr = lane >> 2;
    const int qsw = (lane & 3) ^ ((rr >> 1) & 3);
    const unsigned short* gsrc[4];
    unsigned short* ldst[4];
    if (wave < 2) {
#pragma unroll
        for (int i = 0; i < 4; ++i) {
            int row = wave * 64 + i * 16 + rr;
            int slot = slots_s[row];
            int tok = (slot >= 0) ? (slot >> 1) : 0;   // clamp tail to token 0
            gsrc[i] = xb + (size_t)tok * DIM + qsw * 8;
            ldst[i] = &As[(wave * 64 + i * 16) * 32];
        }
    } else if (wave == 2) {
#pragma unroll
        for (int i = 0; i < 4; ++i) {
            int row = i * 16 + rr;
            gsrc[i] = w1b + ((size_t)e * HID + n0 + row) * DIM + qsw * 8;
            ldst[i] = &B1s[(i * 16) * 32];
        }
    } else {
#pragma unroll
        for (int i = 0; i < 4; ++i) {
            int row = i * 16 + rr;
            gsrc[i] = w3b + ((size_t)e * HID + n0 + row) * DIM + qsw * 8;
            ldst[i] = &B2s[(i * 16) * 32];
        }
    }

    const int wm = wave >> 1, wn = wave & 1;
    const int lrow = lane & 15, quad = lane >> 4;
    // read-side swizzled k-offset (ushorts)
    const int ksw = (quad ^ ((lrow >> 1) & 3)) * 8;

    f32x4 acc1[4][2], acc2[4][2];
    const f32x4 zf = {0.f, 0.f, 0.f, 0.f};
#pragma unroll
    for (int mi = 0; mi < 4; ++mi)
#pragma unroll
        for (int ni = 0; ni < 2; ++ni) { acc1[mi][ni] = zf; acc2[mi][ni] = zf; }

    for (int k0 = 0; k0 < DIM; k0 += 32) {
#pragma unroll
        for (int i = 0; i < 4; ++i) gl_lds16(gsrc[i], ldst[i]);
#pragma unroll
        for (int i = 0; i < 4; ++i) gsrc[i] += 32;
        __syncthreads();

        bf16x8 af[4], b1f[2], b2f[2];
#pragma unroll
        for (int mi = 0; mi < 4; ++mi)
            af[mi] = *(const bf16x8*)&As[(wm * 64 + mi * 16 + lrow) * 32 + ksw];
#pragma unroll
        for (int ni = 0; ni < 2; ++ni) {
            b1f[ni] = *(const bf16x8*)&B1s[(wn * 32 + ni * 16 + lrow) * 32 + ksw];
            b2f[ni] = *(const bf16x8*)&B2s[(wn * 32 + ni * 16 + lrow) * 32 + ksw];
        }
#pragma unroll
        for (int mi = 0; mi < 4; ++mi)
#pragma unroll
            for (int ni = 0; ni < 2; ++ni) {
                acc1[mi][ni] = __builtin_amdgcn_mfma_f32_16x16x32_bf16(
                    af[mi], b1f[ni], acc1[mi][ni], 0, 0, 0);
                acc2[mi][ni] = __builtin_amdgcn_mfma_f32_16x16x32_bf16(
                    af[mi], b2f[ni], acc2[mi][ni], 0, 0, 0);
            }
        __syncthreads();
    }

    // epilogue: h = silu(a1) * a3 -> bf16 h_ws[slot, n]
#pragma unroll
    for (int mi = 0; mi < 4; ++mi) {
#pragma unroll
        for (int r = 0; r < 4; ++r) {
            int mloc = wm * 64 + mi * 16 + quad * 4 + r;
            int slot = slots_s[mloc];
            if (slot >= 0) {
                unsigned short* hrow =
                    h_ws + (size_t)slot * HID + n0 + wn * 32 + lrow;
#pragma unroll
                for (int ni = 0; ni < 2; ++ni) {
                    float a1 = acc1[mi][ni][r], a3 = acc2[mi][ni][r];
                    float hv = (a1 / (1.f + __expf(-a1))) * a3;
                    hrow[ni * 16] = (unsigned short)(f2bf_u(hv) >> 16);
                }
            }
        }
    }
}

// ---------------------------------------------------------------------------
// Kernel 3: gathered GEMM y = h @ w2^T, scale by routing weight, atomicAdd
// into out. C-tile 128 x 128, same quarter swizzle. grid (8, ceilT/128, NEXP).
// ---------------------------------------------------------------------------
__global__ __launch_bounds__(256) void ffn2_k(
    const unsigned short* __restrict__ h_ws, const unsigned short* __restrict__ w2b,
    const int* __restrict__ cnt, const int* __restrict__ slot_list,
    const float* __restrict__ slot_w, float* __restrict__ out)
{
    __shared__ unsigned short As[128 * 32];
    __shared__ unsigned short Bs[128 * 32];
    __shared__ int slots_s[128];
    __shared__ float wgt_s[128];

    const int e = blockIdx.z;
    const int cntE = cnt[e];
    const int m0 = blockIdx.y * 128;
    if (m0 >= cntE) return;
    const int n0 = blockIdx.x * 128;
    const int tid = threadIdx.x;
    const int wave = tid >> 6, lane = tid & 63;

    if (tid < 128) {
        int idx = m0 + tid;
        int s = (idx < cntE) ? slot_list[e * T_TOK + idx] : -1;
        slots_s[tid] = s;
        wgt_s[tid] = (s >= 0) ? slot_w[s] : 0.f;
    }
    __syncthreads();

    // staging: waves 0,1 -> A (gathered h rows); waves 2,3 -> w2 rows.
    const int rr = lane >> 2;
    const int qsw = (lane & 3) ^ ((rr >> 1) & 3);
    const unsigned short* gsrc[4];
    unsigned short* ldst[4];
    if (wave < 2) {
#pragma unroll
        for (int i = 0; i < 4; ++i) {
            int row = wave * 64 + i * 16 + rr;
            int slot = slots_s[row];
            int s = (slot >= 0) ? slot : 0;
            gsrc[i] = h_ws + (size_t)s * HID + qsw * 8;
            ldst[i] = &As[(wave * 64 + i * 16) * 32];
        }
    } else {
#pragma unroll
        for (int i = 0; i < 4; ++i) {
            int row = (wave - 2) * 64 + i * 16 + rr;
            gsrc[i] = w2b + ((size_t)e * DIM + n0 + row) * HID + qsw * 8;
            ldst[i] = &Bs[((wave - 2) * 64 + i * 16) * 32];
        }
    }

    const int wm = wave >> 1, wn = wave & 1;
    const int lrow = lane & 15, quad = lane >> 4;
    const int ksw = (quad ^ ((lrow >> 1) & 3)) * 8;

    f32x4 acc[4][4];
    const f32x4 zf = {0.f, 0.f, 0.f, 0.f};
#pragma unroll
    for (int mi = 0; mi < 4; ++mi)
#pragma unroll
        for (int ni = 0; ni < 4; ++ni) acc[mi][ni] = zf;

    for (int k0 = 0; k0 < HID; k0 += 32) {
#pragma unroll
        for (int i = 0; i < 4; ++i) gl_lds16(gsrc[i], ldst[i]);
#pragma unroll
        for (int i = 0; i < 4; ++i) gsrc[i] += 32;
        __syncthreads();

        bf16x8 af[4], bf[4];
#pragma unroll
        for (int mi = 0; mi < 4; ++mi)
            af[mi] = *(const bf16x8*)&As[(wm * 64 + mi * 16 + lrow) * 32 + ksw];
#pragma unroll
        for (int ni = 0; ni < 4; ++ni)
            bf[ni] = *(const bf16x8*)&Bs[(wn * 64 + ni * 16 + lrow) * 32 + ksw];
#pragma unroll
        for (int mi = 0; mi < 4; ++mi)
#pragma unroll
            for (int ni = 0; ni < 4; ++ni)
                acc[mi][ni] = __builtin_amdgcn_mfma_f32_16x16x32_bf16(
                    af[mi], bf[ni], acc[mi][ni], 0, 0, 0);
        __syncthreads();
    }

#pragma unroll
    for (int mi = 0; mi < 4; ++mi) {
#pragma unroll
        for (int r = 0; r < 4; ++r) {
            int mloc = wm * 64 + mi * 16 + quad * 4 + r;
            int slot = slots_s[mloc];
            if (slot >= 0) {
                int tok = slot >> 1;
                float w = wgt_s[mloc];
                float* orow = out + (size_t)tok * DIM + n0 + wn * 64 + lrow;
#pragma unroll
                for (int ni = 0; ni < 4; ++ni)
                    atomicAdd(&orow[ni * 16], acc[mi][ni][r] * w);
            }
        }
    }
}

// ---------------------------------------------------------------------------
// Workspace layout (bytes, all 256-aligned):
//   [0, 256)                 cnt[8]                (memset 0 per launch)
//   [256, +262144)           slot_list[8][8192]
//   [+262144, +65536)        slot_w[16384]
//   [327936, +92274688)      h_ws   bf16 [16384][2816]
//   [92602624, +16777216)    x_bf   bf16 [8192][1024]
//   [109379840, +46137344)   w1_bf  bf16 [8][2816][1024]
//   [155517184, +46137344)   w3_bf
//   [201654528, +46137344)   w2_bf  bf16 [8][1024][2816]
//   total ~247.8 MB
// ---------------------------------------------------------------------------
extern "C" void kernel_launch(void* const* d_in, const int* in_sizes, int n_in,
                              void* d_out, int out_size, void* d_ws, size_t ws_size,
                              hipStream_t stream) {
    const float* x  = (const float*)d_in[0];
    const float* gw = (const float*)d_in[1];
    const float* w1 = (const float*)d_in[2];
    const float* w2 = (const float*)d_in[3];
    const float* w3 = (const float*)d_in[4];
    float* out = (float*)d_out;

    char* ws = (char*)d_ws;
    int*   cnt       = (int*)ws;
    int*   slot_list = (int*)(ws + 256);
    float* slot_w    = (float*)(ws + 256 + NEXP * T_TOK * 4);
    unsigned short* h_ws = (unsigned short*)(ws + 327936);
    unsigned short* x_bf = (unsigned short*)(ws + 92602624);
    unsigned short* w1_bf = (unsigned short*)(ws + 109379840);
    unsigned short* w3_bf = (unsigned short*)(ws + 155517184);
    unsigned short* w2_bf = (unsigned short*)(ws + 201654528);

    hipMemsetAsync(cnt, 0, 256, stream);
    hipMemsetAsync(out, 0, (size_t)T_TOK * DIM * sizeof(float), stream);

    const int nx = T_TOK * DIM / 8;              // 1048576
    const int nw = NEXP * HID * DIM / 8;         // 2883584
    cvt_k<<<(nx + 255) / 256, 256, 0, stream>>>(x, x_bf, nx);
    cvt_k<<<(nw + 255) / 256, 256, 0, stream>>>(w1, w1_bf, nw);
    cvt_k<<<(nw + 255) / 256, 256, 0, stream>>>(w3, w3_bf, nw);
    cvt_k<<<(nw + 255) / 256, 256, 0, stream>>>(w2, w2_bf, nw);

    router_k<<<T_TOK / 4, 256, 0, stream>>>(x, gw, cnt, slot_list, slot_w);
    ffn1_k<<<dim3(HID / 64, T_TOK / 128, NEXP), 256, 0, stream>>>(
        x_bf, w1_bf, w3_bf, cnt, slot_list, h_ws);
    ffn2_k<<<dim3(DIM / 128, T_TOK / 128, NEXP), 256, 0, stream>>>(
        h_ws, w2_bf, cnt, slot_list, slot_w, out);
}